// Round 9
// baseline (355.953 us; speedup 1.0000x reference)
//
#include <hip/hip_runtime.h>
#include <hip/hip_bf16.h>
#include <stdint.h>

#define DIM 64
#define TH  256
#define NN  512
#define IB  4            // queries (i) per main block

typedef __attribute__((ext_vector_type(8))) short bf16x8;
typedef __attribute__((ext_vector_type(4))) float f32x4;

__device__ __forceinline__ short f2bf(float f) {
    union { float f; uint32_t u; } v; v.f = f;
    uint32_t r = v.u + 0x7fffu + ((v.u >> 16) & 1u);
    return (short)(r >> 16);
}

// prep:
//  bid < 256:  8 j's per block: qkv = x@w_qkv; V f32 [b,j,d]; Kneg bf16 [b,j,d] = -k; QW1 f32 [b,j,t]
//  bid >= 256: 8 blocks build Bext bf16 [256 t][128 k] (k<64: M[h,t]=pos_w2@W1; k>=64: W1[d,t]) + cb[t]
// Loop-interchanged: weight loads hoisted out of the jj loops (8x fewer global loads).
__global__ void prep_all(const float* __restrict__ x, const float* __restrict__ w_qkv,
                         const float* __restrict__ attn_w1,
                         const float* __restrict__ pos_w2, const float* __restrict__ pos_b2,
                         const float* __restrict__ attn_b1,
                         float* __restrict__ V, float* __restrict__ QW1, short* __restrict__ Kneg,
                         short* __restrict__ Bg, float* __restrict__ cbg) {
    const int tid = threadIdx.x;  // 256
    if (blockIdx.x >= 256) {
        const int t = (blockIdx.x - 256) * 32 + (tid >> 3);
        const int h0 = (tid & 7) * 8;
        float m[8] = {};
        for (int d = 0; d < DIM; d++) {
            float wa1 = attn_w1[d * TH + t];
            #pragma unroll
            for (int hh = 0; hh < 8; hh++) m[hh] += pos_w2[(h0 + hh) * DIM + d] * wa1;
        }
        #pragma unroll
        for (int hh = 0; hh < 8; hh++) {
            Bg[t * 128 + h0 + hh] = f2bf(m[hh]);
            Bg[t * 128 + 64 + h0 + hh] = f2bf(attn_w1[(h0 + hh) * TH + t]);
        }
        if ((tid & 7) == 0) {
            float cb = attn_b1[t];
            for (int d = 0; d < DIM; d++) cb += pos_b2[d] * attn_w1[d * TH + t];
            cbg[t] = cb;
        }
        return;
    }
    const int b = blockIdx.x >> 6, j0 = (blockIdx.x & 63) * 8;
    __shared__ float xs[8][DIM], qs[8][DIM];
    #pragma unroll
    for (int p = 0; p < 2; p++) {
        int idx = tid + p * 256;
        xs[idx >> 6][idx & 63] = x[(size_t)(b * NN + j0) * DIM + idx];
    }
    __syncthreads();
    if (tid < 192) {
        float acc[8] = {};
        for (int e = 0; e < DIM; e++) {
            float wq = w_qkv[e * 192 + tid];
            #pragma unroll
            for (int jj = 0; jj < 8; jj++) acc[jj] += xs[jj][e] * wq;
        }
        #pragma unroll
        for (int jj = 0; jj < 8; jj++) {
            size_t row = (size_t)(b * NN + j0 + jj) * DIM;
            if (tid < 64)       qs[jj][tid] = acc[jj];
            else if (tid < 128) Kneg[row + (tid - 64)] = f2bf(-acc[jj]);
            else                V[row + (tid - 128)] = acc[jj];
        }
    }
    __syncthreads();
    float aq[8] = {};
    for (int d = 0; d < DIM; d++) {
        float w = attn_w1[d * TH + tid];
        #pragma unroll
        for (int jj = 0; jj < 8; jj++) aq[jj] += qs[jj][d] * w;
    }
    #pragma unroll
    for (int jj = 0; jj < 8; jj++)
        QW1[(size_t)(b * NN + j0 + jj) * TH + tid] = aq[jj];
}

__launch_bounds__(512, 4)   // cap 128 VGPR for 2 blocks/CU (16 waves); ~115 live — margin small, FETCH_SIZE is the spill tripwire
__global__ void ptl_main(const float* __restrict__ pos, const float* __restrict__ pos_w1,
                         const float* __restrict__ pos_b1, const float* __restrict__ pos_w2,
                         const float* __restrict__ pos_b2, const float* __restrict__ attn_w2,
                         const float* __restrict__ V, const float* __restrict__ QW1,
                         const short* __restrict__ Kneg, const short* __restrict__ Bg,
                         const float* __restrict__ cbg, float* __restrict__ out) {
    const int b = blockIdx.x >> 7, i0 = (blockIdx.x & 127) * IB;
    const int tid = threadIdx.x;
    const int wv = tid >> 6, lane = tid & 63;
    const int lhi = lane >> 4, llo = lane & 15;

    __shared__ __align__(16) short Blds[128 * 128]; // 32KB: one t-half; row t (256B=16 segs), seg s at ((s^(t&15))<<4)
    __shared__ float posl[NN][3];                    // 6144
    __shared__ float2 qwl[IB][TH];                   // 8192: {QW1[i,t]+cb[t], w2[t]}
    __shared__ float4 pw4[DIM];                      // 1024: {pos_w1[0..2][h], pos_b1[h]}
    __shared__ float simbuf[IB][NN];                 // 8192 (accumulated across halves; reused as attn)
    __shared__ float aggw[8][IB][2][DIM];            // 16384
    __shared__ float fin[IB][2][DIM];                // 2048
    __shared__ float wred[2][IB][8];                 // 256

    // ---- common stage (no Blds yet) ----
    for (int idx = tid; idx < NN * 3; idx += 512)
        ((float*)posl)[idx] = pos[b * NN * 3 + idx];
    if (tid < TH) {
        float w2 = attn_w2[tid], cb = cbg[tid];
        #pragma unroll
        for (int ii = 0; ii < IB; ii++) {
            float2 q2; q2.x = QW1[(size_t)(b * NN + i0 + ii) * TH + tid] + cb; q2.y = w2;
            qwl[ii][tid] = q2;
        }
    }
    if (tid < DIM) {
        float4 w; w.x = pos_w1[tid]; w.y = pos_w1[DIM + tid];
        w.z = pos_w1[2 * DIM + tid]; w.w = pos_b1[tid];
        pw4[tid] = w;
    }
    // Kneg fragments: i- and half-invariant, in regs for the whole kernel
    bf16x8 knf[4][2];
    #pragma unroll
    for (int jt = 0; jt < 4; jt++) {
        size_t row = (size_t)(b * NN + wv * 64 + jt * 16 + llo) * DIM;
        knf[jt][0] = *(const bf16x8*)(Kneg + row + lhi * 8);
        knf[jt][1] = *(const bf16x8*)(Kneg + row + 32 + lhi * 8);
    }
    __syncthreads();

    const char* mb = (const char*)Blds + llo * 256;
    const int s0 = ((0  + lhi) ^ llo) << 4;
    const int s1 = ((4  + lhi) ^ llo) << 4;
    const int s2 = ((8  + lhi) ^ llo) << 4;
    const int s3 = ((12 + lhi) ^ llo) << 4;

    // ---- main: t split into 2 halves of 128; stage 32KB per half; ii inner ----
    #pragma unroll 1
    for (int half = 0; half < 2; half++) {
        if (half) __syncthreads();                   // all reads of previous half done
        for (int idx = tid; idx < 128 * 16; idx += 512) {    // 2048 16B segs
            int t = idx >> 4, s = idx & 15;
            *(uint4*)((char*)Blds + t * 256 + ((s ^ (t & 15)) << 4)) =
                *(const uint4*)((const char*)Bg + ((size_t)half * 2048 + idx) * 16);
        }
        __syncthreads();

        #pragma unroll 1
        for (int ii = 0; ii < IB; ii++) {
            const float pi0 = posl[i0 + ii][0], pi1 = posl[i0 + ii][1], pi2 = posl[i0 + ii][2];
            bf16x8 gfr[4][2];
            #pragma unroll
            for (int jt = 0; jt < 4; jt++) {
                const int jA = wv * 64 + jt * 16 + llo;
                const float r0 = pi0 - posl[jA][0], r1 = pi1 - posl[jA][1], r2 = pi2 - posl[jA][2];
                #pragma unroll
                for (int kk = 0; kk < 2; kk++) {
                    #pragma unroll
                    for (int e2 = 0; e2 < 4; e2++) {
                        float4 wA = pw4[kk * 32 + lhi * 8 + 2 * e2];
                        float4 wB = pw4[kk * 32 + lhi * 8 + 2 * e2 + 1];
                        float2 p2;
                        p2.x = fmaxf(r0 * wA.x + r1 * wA.y + r2 * wA.z + wA.w, 0.f);
                        p2.y = fmaxf(r0 * wB.x + r1 * wB.y + r2 * wB.z + wB.w, 0.f);
                        union { __hip_bfloat162 h2; uint32_t u; } cv;
                        cv.h2 = __float22bfloat162_rn(p2);
                        ((uint32_t*)&gfr[jt][kk])[e2] = cv.u;
                    }
                }
            }
            float sa[4][4] = {};
            #pragma unroll 4
            for (int tt = 0; tt < 8; tt++) {
                const int t = half * 128 + tt * 16 + llo;
                bf16x8 bf0 = *(const bf16x8*)(mb + tt * 4096 + s0);
                bf16x8 bf1 = *(const bf16x8*)(mb + tt * 4096 + s1);
                bf16x8 bf2 = *(const bf16x8*)(mb + tt * 4096 + s2);
                bf16x8 bf3 = *(const bf16x8*)(mb + tt * 4096 + s3);
                const float2 qw = qwl[ii][t];
                #pragma unroll
                for (int jt = 0; jt < 4; jt++) {
                    f32x4 acc = {0.f, 0.f, 0.f, 0.f};
                    acc = __builtin_amdgcn_mfma_f32_16x16x32_bf16(gfr[jt][0], bf0, acc, 0, 0, 0);
                    acc = __builtin_amdgcn_mfma_f32_16x16x32_bf16(gfr[jt][1], bf1, acc, 0, 0, 0);
                    acc = __builtin_amdgcn_mfma_f32_16x16x32_bf16(knf[jt][0], bf2, acc, 0, 0, 0);
                    acc = __builtin_amdgcn_mfma_f32_16x16x32_bf16(knf[jt][1], bf3, acc, 0, 0, 0);
                    #pragma unroll
                    for (int r = 0; r < 4; r++)
                        sa[jt][r] += fmaxf(acc[r] + qw.x, 0.f) * qw.y;
                }
            }
            #pragma unroll
            for (int jt = 0; jt < 4; jt++) {
                #pragma unroll
                for (int r = 0; r < 4; r++) {
                    float v = sa[jt][r];
                    v += __shfl_xor(v, 1); v += __shfl_xor(v, 2);
                    v += __shfl_xor(v, 4); v += __shfl_xor(v, 8);
                    if (llo == 0) {
                        const int j = wv * 64 + jt * 16 + lhi * 4 + r;
                        if (half == 0) simbuf[ii][j] = v;
                        else           simbuf[ii][j] += v;
                    }
                }
            }
        }
    }
    __syncthreads();

    // ---- softmax per i over j (thread = j) ----
    float sv[IB];
    #pragma unroll
    for (int ii = 0; ii < IB; ii++) {
        float s = simbuf[ii][tid];
        sv[ii] = s;
        float mx = s;
        #pragma unroll
        for (int off = 1; off < 64; off <<= 1) mx = fmaxf(mx, __shfl_xor(mx, off));
        if (lane == 0) wred[0][ii][wv] = mx;
    }
    __syncthreads();
    float pv[IB];
    #pragma unroll
    for (int ii = 0; ii < IB; ii++) {
        float bm = wred[0][ii][0];
        #pragma unroll
        for (int w = 1; w < 8; w++) bm = fmaxf(bm, wred[0][ii][w]);
        float p = __expf(sv[ii] - bm);
        pv[ii] = p;
        float ps = p;
        #pragma unroll
        for (int off = 1; off < 64; off <<= 1) ps += __shfl_xor(ps, off);
        if (lane == 0) wred[1][ii][wv] = ps;
    }
    __syncthreads();
    #pragma unroll
    for (int ii = 0; ii < IB; ii++) {
        float den = 0.f;
        #pragma unroll
        for (int w = 0; w < 8; w++) den += wred[1][ii][w];
        simbuf[ii][tid] = pv[ii] / den;    // attn
    }
    __syncthreads();

    // ---- aggregation: out = attn@V + (attn@G)@pos_w2 + pos_b2; wave = j-range, lane = d ----
    {
        const int d = lane;
        const float4 wd = pw4[d];
        float pia[IB][3];
        #pragma unroll
        for (int ii = 0; ii < IB; ii++) {
            pia[ii][0] = posl[i0 + ii][0]; pia[ii][1] = posl[i0 + ii][1]; pia[ii][2] = posl[i0 + ii][2];
        }
        float av[IB] = {}, ag[IB] = {};
        const float* vb = V + (size_t)(b * NN + wv * 64) * DIM + d;
        #pragma unroll 4
        for (int jj = 0; jj < 64; jj++) {
            const int j = wv * 64 + jj;
            const float vv = vb[jj * DIM];
            const float p0 = posl[j][0], p1 = posl[j][1], p2 = posl[j][2];
            #pragma unroll
            for (int ii = 0; ii < IB; ii++) {
                const float a = simbuf[ii][j];
                av[ii] += a * vv;
                float g = (pia[ii][0] - p0) * wd.x + (pia[ii][1] - p1) * wd.y +
                          (pia[ii][2] - p2) * wd.z + wd.w;
                ag[ii] += a * fmaxf(g, 0.f);
            }
        }
        #pragma unroll
        for (int ii = 0; ii < IB; ii++) {
            aggw[wv][ii][0][d] = av[ii];
            aggw[wv][ii][1][d] = ag[ii];
        }
    }
    __syncthreads();
    {   // reduce over 8 waves: one elem per thread (IB*2*64 = 512)
        const int ii = tid >> 7, pp = (tid >> 6) & 1, d2 = tid & 63;
        float s = 0.f;
        #pragma unroll
        for (int w = 0; w < 8; w++) s += aggw[w][ii][pp][d2];
        fin[ii][pp][d2] = s;
    }
    __syncthreads();
    if (tid < IB * DIM) {
        const int ii = tid >> 6, d2 = tid & 63;
        float o = fin[ii][0][d2] + pos_b2[d2];
        for (int h = 0; h < DIM; h++) o += fin[ii][1][h] * pos_w2[h * DIM + d2];
        out[(size_t)(b * NN + i0 + ii) * DIM + d2] = o;
    }
}

extern "C" void kernel_launch(void* const* d_in, const int* in_sizes, int n_in,
                              void* d_out, int out_size, void* d_ws, size_t ws_size,
                              hipStream_t stream) {
    const float* x       = (const float*)d_in[0];
    const float* pos     = (const float*)d_in[1];
    const float* w_qkv   = (const float*)d_in[2];
    const float* pos_w1  = (const float*)d_in[3];
    const float* pos_b1  = (const float*)d_in[4];
    const float* pos_w2  = (const float*)d_in[5];
    const float* pos_b2  = (const float*)d_in[6];
    const float* attn_w1 = (const float*)d_in[7];
    const float* attn_b1 = (const float*)d_in[8];
    const float* attn_w2 = (const float*)d_in[9];
    // attn_b2 (d_in[10]) is softmax-invariant -> unused

    char* ws = (char*)d_ws;
    short* Bg   = (short*)(ws + 0);          //  65536 B  Bext bf16 [256][128]
    float* cbg  = (float*)(ws + 65536);      //   1024 B
    float* Vw   = (float*)(ws + 66560);      // 524288 B  V f32
    float* QW1  = (float*)(ws + 590848);     // 2097152 B q@W1 f32
    short* Kneg = (short*)(ws + 2688000);    // 262144 B  -k bf16   (total ~2.95 MB)

    float* outp = (float*)d_out;

    prep_all<<<264, 256, 0, stream>>>(x, w_qkv, attn_w1, pos_w2, pos_b2, attn_b1,
                                      Vw, QW1, Kneg, Bg, cbg);
    ptl_main<<<4 * (NN / IB), 512, 0, stream>>>(pos, pos_w1, pos_b1, pos_w2, pos_b2,
                                                attn_w2, Vw, QW1, Kneg, Bg, cbg, outp);
}

// Round 10
// 234.318 us; speedup vs baseline: 1.5191x; 1.5191x over previous
//
#include <hip/hip_runtime.h>
#include <hip/hip_bf16.h>
#include <stdint.h>

#define DIM 64
#define TH  256
#define NN  512
#define IB  4            // queries (i) per main block

typedef __attribute__((ext_vector_type(8))) short bf16x8;
typedef __attribute__((ext_vector_type(4))) float f32x4;

__device__ __forceinline__ short f2bf(float f) {
    union { float f; uint32_t u; } v; v.f = f;
    uint32_t r = v.u + 0x7fffu + ((v.u >> 16) & 1u);
    return (short)(r >> 16);
}

// prep:
//  bid < 256:  8 j's per block: qkv = x@w_qkv; V f32 [b,j,d]; Kneg bf16 [b,j,d] = -k; QW1 f32 [b,j,t]
//  bid >= 256: 8 blocks build Bext bf16 [256 t][128 k] (k<64: M[h,t]=pos_w2@W1; k>=64: W1[d,t]) + cb[t]
// Loop-interchanged: weight loads hoisted out of the jj loops (8x fewer global loads).
__global__ void prep_all(const float* __restrict__ x, const float* __restrict__ w_qkv,
                         const float* __restrict__ attn_w1,
                         const float* __restrict__ pos_w2, const float* __restrict__ pos_b2,
                         const float* __restrict__ attn_b1,
                         float* __restrict__ V, float* __restrict__ QW1, short* __restrict__ Kneg,
                         short* __restrict__ Bg, float* __restrict__ cbg) {
    const int tid = threadIdx.x;  // 256
    if (blockIdx.x >= 256) {
        const int t = (blockIdx.x - 256) * 32 + (tid >> 3);
        const int h0 = (tid & 7) * 8;
        float m[8] = {};
        for (int d = 0; d < DIM; d++) {
            float wa1 = attn_w1[d * TH + t];
            #pragma unroll
            for (int hh = 0; hh < 8; hh++) m[hh] += pos_w2[(h0 + hh) * DIM + d] * wa1;
        }
        #pragma unroll
        for (int hh = 0; hh < 8; hh++) {
            Bg[t * 128 + h0 + hh] = f2bf(m[hh]);
            Bg[t * 128 + 64 + h0 + hh] = f2bf(attn_w1[(h0 + hh) * TH + t]);
        }
        if ((tid & 7) == 0) {
            float cb = attn_b1[t];
            for (int d = 0; d < DIM; d++) cb += pos_b2[d] * attn_w1[d * TH + t];
            cbg[t] = cb;
        }
        return;
    }
    const int b = blockIdx.x >> 6, j0 = (blockIdx.x & 63) * 8;
    __shared__ float xs[8][DIM], qs[8][DIM];
    #pragma unroll
    for (int p = 0; p < 2; p++) {
        int idx = tid + p * 256;
        xs[idx >> 6][idx & 63] = x[(size_t)(b * NN + j0) * DIM + idx];
    }
    __syncthreads();
    if (tid < 192) {
        float acc[8] = {};
        for (int e = 0; e < DIM; e++) {
            float wq = w_qkv[e * 192 + tid];
            #pragma unroll
            for (int jj = 0; jj < 8; jj++) acc[jj] += xs[jj][e] * wq;
        }
        #pragma unroll
        for (int jj = 0; jj < 8; jj++) {
            size_t row = (size_t)(b * NN + j0 + jj) * DIM;
            if (tid < 64)       qs[jj][tid] = acc[jj];
            else if (tid < 128) Kneg[row + (tid - 64)] = f2bf(-acc[jj]);
            else                V[row + (tid - 128)] = acc[jj];
        }
    }
    __syncthreads();
    float aq[8] = {};
    for (int d = 0; d < DIM; d++) {
        float w = attn_w1[d * TH + tid];
        #pragma unroll
        for (int jj = 0; jj < 8; jj++) aq[jj] += qs[jj][d] * w;
    }
    #pragma unroll
    for (int jj = 0; jj < 8; jj++)
        QW1[(size_t)(b * NN + j0 + jj) * TH + tid] = aq[jj];
}

__launch_bounds__(512, 2)   // NO tight VGPR cap: (512,4)'s 128-cap caused 885MB/dispatch scratch spill (round 9).
                            // Natural allocation is ~112 (round 7) <= 128, so 73.5KB LDS + ~112 VGPR -> 2 blocks/CU anyway.
__global__ void ptl_main(const float* __restrict__ pos, const float* __restrict__ pos_w1,
                         const float* __restrict__ pos_b1, const float* __restrict__ pos_w2,
                         const float* __restrict__ pos_b2, const float* __restrict__ attn_w2,
                         const float* __restrict__ V, const float* __restrict__ QW1,
                         const short* __restrict__ Kneg, const short* __restrict__ Bg,
                         const float* __restrict__ cbg, float* __restrict__ out) {
    const int b = blockIdx.x >> 7, i0 = (blockIdx.x & 127) * IB;
    const int tid = threadIdx.x;
    const int wv = tid >> 6, lane = tid & 63;
    const int lhi = lane >> 4, llo = lane & 15;

    __shared__ __align__(16) short Blds[128 * 128]; // 32KB: one t-half; row t (256B=16 segs), seg s at ((s^(t&15))<<4)
    __shared__ float posl[NN][3];                    // 6144
    __shared__ float2 qwl[IB][TH];                   // 8192: {QW1[i,t]+cb[t], w2[t]}
    __shared__ float4 pw4[DIM];                      // 1024: {pos_w1[0..2][h], pos_b1[h]}
    __shared__ float simbuf[IB][NN];                 // 8192 (accumulated across halves; reused as attn)
    __shared__ float aggw[8][IB][2][DIM];            // 16384
    __shared__ float fin[IB][2][DIM];                // 2048
    __shared__ float wred[2][IB][8];                 // 256

    // ---- common stage (no Blds yet) ----
    for (int idx = tid; idx < NN * 3; idx += 512)
        ((float*)posl)[idx] = pos[b * NN * 3 + idx];
    if (tid < TH) {
        float w2 = attn_w2[tid], cb = cbg[tid];
        #pragma unroll
        for (int ii = 0; ii < IB; ii++) {
            float2 q2; q2.x = QW1[(size_t)(b * NN + i0 + ii) * TH + tid] + cb; q2.y = w2;
            qwl[ii][tid] = q2;
        }
    }
    if (tid < DIM) {
        float4 w; w.x = pos_w1[tid]; w.y = pos_w1[DIM + tid];
        w.z = pos_w1[2 * DIM + tid]; w.w = pos_b1[tid];
        pw4[tid] = w;
    }
    // Kneg fragments: i- and half-invariant, in regs for the whole kernel
    bf16x8 knf[4][2];
    #pragma unroll
    for (int jt = 0; jt < 4; jt++) {
        size_t row = (size_t)(b * NN + wv * 64 + jt * 16 + llo) * DIM;
        knf[jt][0] = *(const bf16x8*)(Kneg + row + lhi * 8);
        knf[jt][1] = *(const bf16x8*)(Kneg + row + 32 + lhi * 8);
    }
    __syncthreads();

    const char* mb = (const char*)Blds + llo * 256;
    const int s0 = ((0  + lhi) ^ llo) << 4;
    const int s1 = ((4  + lhi) ^ llo) << 4;
    const int s2 = ((8  + lhi) ^ llo) << 4;
    const int s3 = ((12 + lhi) ^ llo) << 4;

    // ---- main: t split into 2 halves of 128; stage 32KB per half; ii inner ----
    #pragma unroll 1
    for (int half = 0; half < 2; half++) {
        if (half) __syncthreads();                   // all reads of previous half done
        for (int idx = tid; idx < 128 * 16; idx += 512) {    // 2048 16B segs
            int t = idx >> 4, s = idx & 15;
            *(uint4*)((char*)Blds + t * 256 + ((s ^ (t & 15)) << 4)) =
                *(const uint4*)((const char*)Bg + ((size_t)half * 2048 + idx) * 16);
        }
        __syncthreads();

        #pragma unroll 1
        for (int ii = 0; ii < IB; ii++) {
            const float pi0 = posl[i0 + ii][0], pi1 = posl[i0 + ii][1], pi2 = posl[i0 + ii][2];
            bf16x8 gfr[4][2];
            #pragma unroll
            for (int jt = 0; jt < 4; jt++) {
                const int jA = wv * 64 + jt * 16 + llo;
                const float r0 = pi0 - posl[jA][0], r1 = pi1 - posl[jA][1], r2 = pi2 - posl[jA][2];
                #pragma unroll
                for (int kk = 0; kk < 2; kk++) {
                    #pragma unroll
                    for (int e2 = 0; e2 < 4; e2++) {
                        float4 wA = pw4[kk * 32 + lhi * 8 + 2 * e2];
                        float4 wB = pw4[kk * 32 + lhi * 8 + 2 * e2 + 1];
                        float2 p2;
                        p2.x = fmaxf(r0 * wA.x + r1 * wA.y + r2 * wA.z + wA.w, 0.f);
                        p2.y = fmaxf(r0 * wB.x + r1 * wB.y + r2 * wB.z + wB.w, 0.f);
                        union { __hip_bfloat162 h2; uint32_t u; } cv;
                        cv.h2 = __float22bfloat162_rn(p2);
                        ((uint32_t*)&gfr[jt][kk])[e2] = cv.u;
                    }
                }
            }
            float sa[4][4] = {};
            #pragma unroll 4
            for (int tt = 0; tt < 8; tt++) {
                const int t = half * 128 + tt * 16 + llo;
                bf16x8 bf0 = *(const bf16x8*)(mb + tt * 4096 + s0);
                bf16x8 bf1 = *(const bf16x8*)(mb + tt * 4096 + s1);
                bf16x8 bf2 = *(const bf16x8*)(mb + tt * 4096 + s2);
                bf16x8 bf3 = *(const bf16x8*)(mb + tt * 4096 + s3);
                const float2 qw = qwl[ii][t];
                #pragma unroll
                for (int jt = 0; jt < 4; jt++) {
                    f32x4 acc = {0.f, 0.f, 0.f, 0.f};
                    acc = __builtin_amdgcn_mfma_f32_16x16x32_bf16(gfr[jt][0], bf0, acc, 0, 0, 0);
                    acc = __builtin_amdgcn_mfma_f32_16x16x32_bf16(gfr[jt][1], bf1, acc, 0, 0, 0);
                    acc = __builtin_amdgcn_mfma_f32_16x16x32_bf16(knf[jt][0], bf2, acc, 0, 0, 0);
                    acc = __builtin_amdgcn_mfma_f32_16x16x32_bf16(knf[jt][1], bf3, acc, 0, 0, 0);
                    #pragma unroll
                    for (int r = 0; r < 4; r++)
                        sa[jt][r] += fmaxf(acc[r] + qw.x, 0.f) * qw.y;
                }
            }
            #pragma unroll
            for (int jt = 0; jt < 4; jt++) {
                #pragma unroll
                for (int r = 0; r < 4; r++) {
                    float v = sa[jt][r];
                    v += __shfl_xor(v, 1); v += __shfl_xor(v, 2);
                    v += __shfl_xor(v, 4); v += __shfl_xor(v, 8);
                    if (llo == 0) {
                        const int j = wv * 64 + jt * 16 + lhi * 4 + r;
                        if (half == 0) simbuf[ii][j] = v;
                        else           simbuf[ii][j] += v;
                    }
                }
            }
        }
    }
    __syncthreads();

    // ---- softmax per i over j (thread = j) ----
    float sv[IB];
    #pragma unroll
    for (int ii = 0; ii < IB; ii++) {
        float s = simbuf[ii][tid];
        sv[ii] = s;
        float mx = s;
        #pragma unroll
        for (int off = 1; off < 64; off <<= 1) mx = fmaxf(mx, __shfl_xor(mx, off));
        if (lane == 0) wred[0][ii][wv] = mx;
    }
    __syncthreads();
    float pv[IB];
    #pragma unroll
    for (int ii = 0; ii < IB; ii++) {
        float bm = wred[0][ii][0];
        #pragma unroll
        for (int w = 1; w < 8; w++) bm = fmaxf(bm, wred[0][ii][w]);
        float p = __expf(sv[ii] - bm);
        pv[ii] = p;
        float ps = p;
        #pragma unroll
        for (int off = 1; off < 64; off <<= 1) ps += __shfl_xor(ps, off);
        if (lane == 0) wred[1][ii][wv] = ps;
    }
    __syncthreads();
    #pragma unroll
    for (int ii = 0; ii < IB; ii++) {
        float den = 0.f;
        #pragma unroll
        for (int w = 0; w < 8; w++) den += wred[1][ii][w];
        simbuf[ii][tid] = pv[ii] / den;    // attn
    }
    __syncthreads();

    // ---- aggregation: out = attn@V + (attn@G)@pos_w2 + pos_b2; wave = j-range, lane = d ----
    {
        const int d = lane;
        const float4 wd = pw4[d];
        float pia[IB][3];
        #pragma unroll
        for (int ii = 0; ii < IB; ii++) {
            pia[ii][0] = posl[i0 + ii][0]; pia[ii][1] = posl[i0 + ii][1]; pia[ii][2] = posl[i0 + ii][2];
        }
        float av[IB] = {}, ag[IB] = {};
        const float* vb = V + (size_t)(b * NN + wv * 64) * DIM + d;
        #pragma unroll 4
        for (int jj = 0; jj < 64; jj++) {
            const int j = wv * 64 + jj;
            const float vv = vb[jj * DIM];
            const float p0 = posl[j][0], p1 = posl[j][1], p2 = posl[j][2];
            #pragma unroll
            for (int ii = 0; ii < IB; ii++) {
                const float a = simbuf[ii][j];
                av[ii] += a * vv;
                float g = (pia[ii][0] - p0) * wd.x + (pia[ii][1] - p1) * wd.y +
                          (pia[ii][2] - p2) * wd.z + wd.w;
                ag[ii] += a * fmaxf(g, 0.f);
            }
        }
        #pragma unroll
        for (int ii = 0; ii < IB; ii++) {
            aggw[wv][ii][0][d] = av[ii];
            aggw[wv][ii][1][d] = ag[ii];
        }
    }
    __syncthreads();
    {   // reduce over 8 waves: one elem per thread (IB*2*64 = 512)
        const int ii = tid >> 7, pp = (tid >> 6) & 1, d2 = tid & 63;
        float s = 0.f;
        #pragma unroll
        for (int w = 0; w < 8; w++) s += aggw[w][ii][pp][d2];
        fin[ii][pp][d2] = s;
    }
    __syncthreads();
    if (tid < IB * DIM) {
        const int ii = tid >> 6, d2 = tid & 63;
        float o = fin[ii][0][d2] + pos_b2[d2];
        for (int h = 0; h < DIM; h++) o += fin[ii][1][h] * pos_w2[h * DIM + d2];
        out[(size_t)(b * NN + i0 + ii) * DIM + d2] = o;
    }
}

extern "C" void kernel_launch(void* const* d_in, const int* in_sizes, int n_in,
                              void* d_out, int out_size, void* d_ws, size_t ws_size,
                              hipStream_t stream) {
    const float* x       = (const float*)d_in[0];
    const float* pos     = (const float*)d_in[1];
    const float* w_qkv   = (const float*)d_in[2];
    const float* pos_w1  = (const float*)d_in[3];
    const float* pos_b1  = (const float*)d_in[4];
    const float* pos_w2  = (const float*)d_in[5];
    const float* pos_b2  = (const float*)d_in[6];
    const float* attn_w1 = (const float*)d_in[7];
    const float* attn_b1 = (const float*)d_in[8];
    const float* attn_w2 = (const float*)d_in[9];
    // attn_b2 (d_in[10]) is softmax-invariant -> unused

    char* ws = (char*)d_ws;
    short* Bg   = (short*)(ws + 0);          //  65536 B  Bext bf16 [256][128]
    float* cbg  = (float*)(ws + 65536);      //   1024 B
    float* Vw   = (float*)(ws + 66560);      // 524288 B  V f32
    float* QW1  = (float*)(ws + 590848);     // 2097152 B q@W1 f32
    short* Kneg = (short*)(ws + 2688000);    // 262144 B  -k bf16   (total ~2.95 MB)

    float* outp = (float*)d_out;

    prep_all<<<264, 256, 0, stream>>>(x, w_qkv, attn_w1, pos_w2, pos_b2, attn_b1,
                                      Vw, QW1, Kneg, Bg, cbg);
    ptl_main<<<4 * (NN / IB), 512, 0, stream>>>(pos, pos_w1, pos_b1, pos_w2, pos_b2,
                                                attn_w2, Vw, QW1, Kneg, Bg, cbg, outp);
}

// Round 11
// 208.266 us; speedup vs baseline: 1.7091x; 1.1251x over previous
//
#include <hip/hip_runtime.h>
#include <hip/hip_bf16.h>
#include <stdint.h>

#define DIM 64
#define TH  256
#define NN  512
#define IB  8            // queries (i) per main block (16-wave block)

typedef __attribute__((ext_vector_type(8))) short bf16x8;
typedef __attribute__((ext_vector_type(4))) float f32x4;

__device__ __forceinline__ short f2bf(float f) {
    union { float f; uint32_t u; } v; v.f = f;
    uint32_t r = v.u + 0x7fffu + ((v.u >> 16) & 1u);
    return (short)(r >> 16);
}

// prep (unchanged from round 10):
//  bid < 256:  8 j's per block: qkv = x@w_qkv; V f32 [b,j,d]; Kneg bf16 [b,j,d] = -k; QW1 f32 [b,j,t]
//  bid >= 256: 8 blocks build Bext bf16 [256 t][128 k] (k<64: M; k>=64: W1) + cb[t]
__global__ void prep_all(const float* __restrict__ x, const float* __restrict__ w_qkv,
                         const float* __restrict__ attn_w1,
                         const float* __restrict__ pos_w2, const float* __restrict__ pos_b2,
                         const float* __restrict__ attn_b1,
                         float* __restrict__ V, float* __restrict__ QW1, short* __restrict__ Kneg,
                         short* __restrict__ Bg, float* __restrict__ cbg) {
    const int tid = threadIdx.x;  // 256
    if (blockIdx.x >= 256) {
        const int t = (blockIdx.x - 256) * 32 + (tid >> 3);
        const int h0 = (tid & 7) * 8;
        float m[8] = {};
        for (int d = 0; d < DIM; d++) {
            float wa1 = attn_w1[d * TH + t];
            #pragma unroll
            for (int hh = 0; hh < 8; hh++) m[hh] += pos_w2[(h0 + hh) * DIM + d] * wa1;
        }
        #pragma unroll
        for (int hh = 0; hh < 8; hh++) {
            Bg[t * 128 + h0 + hh] = f2bf(m[hh]);
            Bg[t * 128 + 64 + h0 + hh] = f2bf(attn_w1[(h0 + hh) * TH + t]);
        }
        if ((tid & 7) == 0) {
            float cb = attn_b1[t];
            for (int d = 0; d < DIM; d++) cb += pos_b2[d] * attn_w1[d * TH + t];
            cbg[t] = cb;
        }
        return;
    }
    const int b = blockIdx.x >> 6, j0 = (blockIdx.x & 63) * 8;
    __shared__ float xs[8][DIM], qs[8][DIM];
    #pragma unroll
    for (int p = 0; p < 2; p++) {
        int idx = tid + p * 256;
        xs[idx >> 6][idx & 63] = x[(size_t)(b * NN + j0) * DIM + idx];
    }
    __syncthreads();
    if (tid < 192) {
        float acc[8] = {};
        for (int e = 0; e < DIM; e++) {
            float wq = w_qkv[e * 192 + tid];
            #pragma unroll
            for (int jj = 0; jj < 8; jj++) acc[jj] += xs[jj][e] * wq;
        }
        #pragma unroll
        for (int jj = 0; jj < 8; jj++) {
            size_t row = (size_t)(b * NN + j0 + jj) * DIM;
            if (tid < 64)       qs[jj][tid] = acc[jj];
            else if (tid < 128) Kneg[row + (tid - 64)] = f2bf(-acc[jj]);
            else                V[row + (tid - 128)] = acc[jj];
        }
    }
    __syncthreads();
    float aq[8] = {};
    for (int d = 0; d < DIM; d++) {
        float w = attn_w1[d * TH + tid];
        #pragma unroll
        for (int jj = 0; jj < 8; jj++) aq[jj] += qs[jj][d] * w;
    }
    #pragma unroll
    for (int jj = 0; jj < 8; jj++)
        QW1[(size_t)(b * NN + j0 + jj) * TH + tid] = aq[jj];
}

// 16-wave block: one block fills a CU (16 waves = 4/SIMD). Each wave owns 32 j's
// -> knf/gfr halved vs the 8-wave version => ~100 live VGPR under the 128 cap (no spill).
__launch_bounds__(1024, 4)
__global__ void ptl_main(const float* __restrict__ pos, const float* __restrict__ pos_w1,
                         const float* __restrict__ pos_b1, const float* __restrict__ pos_w2,
                         const float* __restrict__ pos_b2, const float* __restrict__ attn_w2,
                         const float* __restrict__ V, const float* __restrict__ QW1,
                         const short* __restrict__ Kneg, const short* __restrict__ Bg,
                         const float* __restrict__ cbg, float* __restrict__ out) {
    const int b = blockIdx.x >> 6, i0 = (blockIdx.x & 63) * IB;
    const int tid = threadIdx.x;
    const int wv = tid >> 6, lane = tid & 63;     // wv in [0,16)
    const int lhi = lane >> 4, llo = lane & 15;

    __shared__ __align__(16) short Blds[TH * 128]; // 64KB, swizzled: t*256 + ((s^(t&15))<<4)
    __shared__ float posl[NN][3];                  // 6KB
    __shared__ float2 qwl[IB][TH];                 // 16KB {QW1[i,t]+cb[t], w2[t]}
    __shared__ float4 pw4[DIM];                    // 1KB
    __shared__ float simbuf[IB][NN];               // 16KB (scores -> attn)
    __shared__ float aggw[16][4][2][DIM];          // 32KB (reused for 2 ii-groups)
    __shared__ float fin[IB][2][DIM];              // 4KB
    __shared__ float wred[2][IB][8];               // max/sum partials per 8-wave group

    // ---- stage ----
    #pragma unroll
    for (int p = 0; p < 4; p++) {                  // 4096 16B segs / 1024 thr
        int idx = tid + p * 1024;
        int t = idx >> 4, s = idx & 15;
        *(uint4*)((char*)Blds + t * 256 + ((s ^ (t & 15)) << 4)) =
            *(const uint4*)((const char*)Bg + (size_t)idx * 16);
    }
    #pragma unroll
    for (int p = 0; p < 2; p++) {
        int idx = tid + p * 1024;
        if (idx < NN * 3) ((float*)posl)[idx] = pos[b * NN * 3 + idx];
    }
    #pragma unroll
    for (int p = 0; p < 2; p++) {                  // IB*TH = 2048 entries
        int idx = tid + p * 1024;
        int ii = idx >> 8, t = idx & 255;
        float2 q2;
        q2.x = QW1[(size_t)(b * NN + i0 + ii) * TH + t] + cbg[t];
        q2.y = attn_w2[t];
        qwl[ii][t] = q2;
    }
    if (tid < DIM) {
        float4 w; w.x = pos_w1[tid]; w.y = pos_w1[DIM + tid];
        w.z = pos_w1[2 * DIM + tid]; w.w = pos_b1[tid];
        pw4[tid] = w;
    }
    // Kneg fragments: wave's 32 j's, i-invariant, in regs for the whole kernel
    bf16x8 knf[2][2];
    #pragma unroll
    for (int jt = 0; jt < 2; jt++) {
        size_t row = (size_t)(b * NN + wv * 32 + jt * 16 + llo) * DIM;
        knf[jt][0] = *(const bf16x8*)(Kneg + row + lhi * 8);
        knf[jt][1] = *(const bf16x8*)(Kneg + row + 32 + lhi * 8);
    }
    __syncthreads();

    const char* mb = (const char*)Blds + llo * 256;
    const int s0 = ((0  + lhi) ^ llo) << 4;
    const int s1 = ((4  + lhi) ^ llo) << 4;
    const int s2 = ((8  + lhi) ^ llo) << 4;
    const int s3 = ((12 + lhi) ^ llo) << 4;

    // ---- main: per i, sim over this wave's 32-j range, K=128 MFMA ----
    #pragma unroll 1
    for (int ii = 0; ii < IB; ii++) {
        const float pi0 = posl[i0 + ii][0], pi1 = posl[i0 + ii][1], pi2 = posl[i0 + ii][2];
        bf16x8 gfr[2][2];
        #pragma unroll
        for (int jt = 0; jt < 2; jt++) {
            const int jA = wv * 32 + jt * 16 + llo;
            const float r0 = pi0 - posl[jA][0], r1 = pi1 - posl[jA][1], r2 = pi2 - posl[jA][2];
            #pragma unroll
            for (int kk = 0; kk < 2; kk++) {
                #pragma unroll
                for (int e2 = 0; e2 < 4; e2++) {
                    float4 wA = pw4[kk * 32 + lhi * 8 + 2 * e2];
                    float4 wB = pw4[kk * 32 + lhi * 8 + 2 * e2 + 1];
                    float2 p2;
                    p2.x = fmaxf(r0 * wA.x + r1 * wA.y + r2 * wA.z + wA.w, 0.f);
                    p2.y = fmaxf(r0 * wB.x + r1 * wB.y + r2 * wB.z + wB.w, 0.f);
                    union { __hip_bfloat162 h2; uint32_t u; } cv;
                    cv.h2 = __float22bfloat162_rn(p2);
                    ((uint32_t*)&gfr[jt][kk])[e2] = cv.u;
                }
            }
        }
        float sa[2][4] = {};
        #pragma unroll 4
        for (int tt = 0; tt < 16; tt++) {
            const int t = tt * 16 + llo;
            bf16x8 bf0 = *(const bf16x8*)(mb + tt * 4096 + s0);
            bf16x8 bf1 = *(const bf16x8*)(mb + tt * 4096 + s1);
            bf16x8 bf2 = *(const bf16x8*)(mb + tt * 4096 + s2);
            bf16x8 bf3 = *(const bf16x8*)(mb + tt * 4096 + s3);
            const float2 qw = qwl[ii][t];
            #pragma unroll
            for (int jt = 0; jt < 2; jt++) {
                f32x4 acc = {0.f, 0.f, 0.f, 0.f};
                acc = __builtin_amdgcn_mfma_f32_16x16x32_bf16(gfr[jt][0], bf0, acc, 0, 0, 0);
                acc = __builtin_amdgcn_mfma_f32_16x16x32_bf16(gfr[jt][1], bf1, acc, 0, 0, 0);
                acc = __builtin_amdgcn_mfma_f32_16x16x32_bf16(knf[jt][0], bf2, acc, 0, 0, 0);
                acc = __builtin_amdgcn_mfma_f32_16x16x32_bf16(knf[jt][1], bf3, acc, 0, 0, 0);
                #pragma unroll
                for (int r = 0; r < 4; r++)
                    sa[jt][r] += fmaxf(acc[r] + qw.x, 0.f) * qw.y;
            }
        }
        #pragma unroll
        for (int jt = 0; jt < 2; jt++) {
            #pragma unroll
            for (int r = 0; r < 4; r++) {
                float v = sa[jt][r];
                v += __shfl_xor(v, 1); v += __shfl_xor(v, 2);
                v += __shfl_xor(v, 4); v += __shfl_xor(v, 8);
                if (llo == 0) simbuf[ii][wv * 32 + jt * 16 + lhi * 4 + r] = v;
            }
        }
    }
    __syncthreads();

    // ---- softmax per i over j: 2 ii concurrently (iig = wv>>3), 4 sub-passes ----
    const int iig = wv >> 3, w8 = wv & 7, j = tid & 511;
    float sv[4], pv[4];
    #pragma unroll
    for (int c = 0; c < 4; c++) {
        const int ii = 2 * c + iig;
        float s = simbuf[ii][j];
        sv[c] = s;
        float mx = s;
        #pragma unroll
        for (int off = 1; off < 64; off <<= 1) mx = fmaxf(mx, __shfl_xor(mx, off));
        if (lane == 0) wred[0][ii][w8] = mx;
    }
    __syncthreads();
    #pragma unroll
    for (int c = 0; c < 4; c++) {
        const int ii = 2 * c + iig;
        float bm = wred[0][ii][0];
        #pragma unroll
        for (int w = 1; w < 8; w++) bm = fmaxf(bm, wred[0][ii][w]);
        float p = __expf(sv[c] - bm);
        pv[c] = p;
        float ps = p;
        #pragma unroll
        for (int off = 1; off < 64; off <<= 1) ps += __shfl_xor(ps, off);
        if (lane == 0) wred[1][ii][w8] = ps;
    }
    __syncthreads();
    #pragma unroll
    for (int c = 0; c < 4; c++) {
        const int ii = 2 * c + iig;
        float den = 0.f;
        #pragma unroll
        for (int w = 0; w < 8; w++) den += wred[1][ii][w];
        simbuf[ii][j] = pv[c] / den;    // attn
    }
    __syncthreads();

    // ---- aggregation in two ii-groups of 4 (aggw reused): wave = 32-j range, lane = d ----
    #pragma unroll 1
    for (int g = 0; g < 2; g++) {
        if (g) __syncthreads();                    // prior group's aggw reads done
        {
            const int d = lane;
            const float4 wd = pw4[d];
            float av[4] = {}, ag[4] = {};
            const float* vb = V + (size_t)(b * NN + wv * 32) * DIM + d;
            #pragma unroll 4
            for (int jj = 0; jj < 32; jj++) {
                const int jx = wv * 32 + jj;
                const float vv = vb[jj * DIM];
                const float p0 = posl[jx][0], p1 = posl[jx][1], p2 = posl[jx][2];
                #pragma unroll
                for (int c = 0; c < 4; c++) {
                    const int ii = g * 4 + c;
                    const float a = simbuf[ii][jx];
                    av[c] += a * vv;
                    float gg = (posl[i0 + ii][0] - p0) * wd.x + (posl[i0 + ii][1] - p1) * wd.y +
                               (posl[i0 + ii][2] - p2) * wd.z + wd.w;
                    ag[c] += a * fmaxf(gg, 0.f);
                }
            }
            #pragma unroll
            for (int c = 0; c < 4; c++) {
                aggw[wv][c][0][d] = av[c];
                aggw[wv][c][1][d] = ag[c];
            }
        }
        __syncthreads();
        if (tid < 512) {                           // 4 ii x 2 x 64 = 512 elems
            const int c = tid >> 7, pp = (tid >> 6) & 1, d2 = tid & 63;
            float s = 0.f;
            #pragma unroll
            for (int w = 0; w < 16; w++) s += aggw[w][c][pp][d2];
            fin[g * 4 + c][pp][d2] = s;
        }
    }
    __syncthreads();
    if (tid < IB * DIM) {
        const int ii = tid >> 6, d2 = tid & 63;
        float o = fin[ii][0][d2] + pos_b2[d2];
        for (int h = 0; h < DIM; h++) o += fin[ii][1][h] * pos_w2[h * DIM + d2];
        out[(size_t)(b * NN + i0 + ii) * DIM + d2] = o;
    }
}

extern "C" void kernel_launch(void* const* d_in, const int* in_sizes, int n_in,
                              void* d_out, int out_size, void* d_ws, size_t ws_size,
                              hipStream_t stream) {
    const float* x       = (const float*)d_in[0];
    const float* pos     = (const float*)d_in[1];
    const float* w_qkv   = (const float*)d_in[2];
    const float* pos_w1  = (const float*)d_in[3];
    const float* pos_b1  = (const float*)d_in[4];
    const float* pos_w2  = (const float*)d_in[5];
    const float* pos_b2  = (const float*)d_in[6];
    const float* attn_w1 = (const float*)d_in[7];
    const float* attn_b1 = (const float*)d_in[8];
    const float* attn_w2 = (const float*)d_in[9];
    // attn_b2 (d_in[10]) is softmax-invariant -> unused

    char* ws = (char*)d_ws;
    short* Bg   = (short*)(ws + 0);          //  65536 B  Bext bf16 [256][128]
    float* cbg  = (float*)(ws + 65536);      //   1024 B
    float* Vw   = (float*)(ws + 66560);      // 524288 B  V f32
    float* QW1  = (float*)(ws + 590848);     // 2097152 B q@W1 f32
    short* Kneg = (short*)(ws + 2688000);    // 262144 B  -k bf16   (total ~2.95 MB)

    float* outp = (float*)d_out;

    prep_all<<<264, 256, 0, stream>>>(x, w_qkv, attn_w1, pos_w2, pos_b2, attn_b1,
                                      Vw, QW1, Kneg, Bg, cbg);
    ptl_main<<<4 * (NN / IB), 1024, 0, stream>>>(pos, pos_w1, pos_b1, pos_w2, pos_b2,
                                                 attn_w2, Vw, QW1, Kneg, Bg, cbg, outp);
}